// Round 1
// baseline (513.328 us; speedup 1.0000x reference)
//
#include <hip/hip_runtime.h>
#include <math.h>
#include <stdint.h>

#define B_SZ   2
#define N_PTS  8192
#define IN_DIM 64
#define D_IN   70          // 64 features + 6 geom
#define ODIM   128
#define NQ_ALL (B_SZ * N_PTS)
#define RADIUS_F 0.02f

typedef unsigned long long u64;

// ---------------------------------------------------------------------------
// sorted top-10 (ascending) insert via unrolled min/max chain.
// best[] stays in registers (all indices compile-time). Caller guards with
// (key < best[9]).
__device__ __forceinline__ void insert10(u64 (&best)[10], u64 key) {
#pragma unroll
  for (int j = 9; j >= 1; --j) {
    u64 hi = (best[j - 1] > key) ? best[j - 1] : key;   // max(old[j-1], key)
    best[j] = (best[j] < hi) ? best[j] : hi;            // min(old[j], hi)
  }
  best[0] = (best[0] < key) ? best[0] : key;
}

// exact f32 helpers matching the reference's op order (no contraction)
__device__ __forceinline__ float sq3(float x, float y, float z) {
  return __fadd_rn(__fadd_rn(__fmul_rn(x, x), __fmul_rn(y, y)), __fmul_rn(z, z));
}

// ---------------------------------------------------------------------------
// Kernel 0: per-batch masked centroid (f64 reduce -> f32 like ref)
__global__ __launch_bounds__(256) void k_center(const float* __restrict__ points,
                                                const int* __restrict__ mask,
                                                float* __restrict__ centerOut) {
  const int b = blockIdx.x;
  const float* P = points + (size_t)b * N_PTS * 3;
  const int* M = mask + (size_t)b * N_PTS;
  double sx = 0.0, sy = 0.0, sz = 0.0, sc = 0.0;
  for (int i = threadIdx.x; i < N_PTS; i += 256) {
    if (M[i] != 0) {
      sx += (double)P[3 * i + 0];
      sy += (double)P[3 * i + 1];
      sz += (double)P[3 * i + 2];
      sc += 1.0;
    }
  }
  __shared__ double sh[4][256];
  sh[0][threadIdx.x] = sx; sh[1][threadIdx.x] = sy;
  sh[2][threadIdx.x] = sz; sh[3][threadIdx.x] = sc;
  __syncthreads();
  for (int off = 128; off > 0; off >>= 1) {
    if ((int)threadIdx.x < off) {
      sh[0][threadIdx.x] += sh[0][threadIdx.x + off];
      sh[1][threadIdx.x] += sh[1][threadIdx.x + off];
      sh[2][threadIdx.x] += sh[2][threadIdx.x + off];
      sh[3][threadIdx.x] += sh[3][threadIdx.x + off];
    }
    __syncthreads();
  }
  if (threadIdx.x == 0) {
    float cf  = (float)sh[3][0];
    float div = fmaxf(cf, 1.0f);
    centerOut[b * 4 + 0] = (float)sh[0][0] / div;
    centerOut[b * 4 + 1] = (float)sh[1][0] / div;
    centerOut[b * 4 + 2] = (float)sh[2][0] / div;
    centerOut[b * 4 + 3] = (cf > 0.0f) ? 1.0f : 0.0f;   // mask-nonempty flag
  }
}

// ---------------------------------------------------------------------------
// Kernel 1: pairwise pass. grid (N/256, S, B). Each thread owns one query and
// scans candidates [s*L, (s+1)*L) through 512-wide LDS tiles.
// Outputs: per-(query,segment) top-10 u64 keys ((distbits<<32)|idx) and
// density partial. Layouts transposed for coalesced merge reads:
//   keys[(s*10+j)*NQ_ALL + qflat], dens[s*NQ_ALL + qflat].
__global__ __launch_bounds__(256) void k_pairwise(const float* __restrict__ points,
                                                  const int* __restrict__ mask,
                                                  u64* __restrict__ keysOut,
                                                  float* __restrict__ densOut,
                                                  int S, int L) {
  const int b = blockIdx.z;
  const int s = blockIdx.y;
  const int q = blockIdx.x * 256 + threadIdx.x;   // query index within batch
  const float* P = points + (size_t)b * N_PTS * 3;
  const int* M = mask + (size_t)b * N_PTS;

  const float px = P[3 * q + 0];
  const float py = P[3 * q + 1];
  const float pz = P[3 * q + 2];
  const float sqq = sq3(px, py, pz);

  u64 best[10];
#pragma unroll
  for (int j = 0; j < 10; ++j) best[j] = ~0ull;
  float dens = 0.0f;

  __shared__ float raw[512 * 3];
  __shared__ float4 tile[512];
  __shared__ unsigned int tmask[512];

  const int c0 = s * L;
  for (int t = 0; t < L; t += 512) {
    const int base = c0 + t;
    for (int i = threadIdx.x; i < 512 * 3; i += 256) raw[i] = P[(size_t)base * 3 + i];
    for (int i = threadIdx.x; i < 512; i += 256) tmask[i] = (unsigned)(M[base + i] != 0);
    __syncthreads();
    for (int i = threadIdx.x; i < 512; i += 256) {
      float x = raw[3 * i + 0], y = raw[3 * i + 1], z = raw[3 * i + 2];
      tile[i] = make_float4(x, y, z, sq3(x, y, z));
    }
    __syncthreads();

#pragma unroll 2
    for (int c = 0; c < 512; ++c) {
      float4 tp = tile[c];
      unsigned m = tmask[c];
      // reference order: dot = fma(z, ., fma(y, ., x*x)); d2 = (sqi+sqj) - 2*dot
      float dot = __fmaf_rn(pz, tp.z, __fmaf_rn(py, tp.y, __fmul_rn(px, tp.x)));
      float d2  = __fsub_rn(__fadd_rn(sqq, tp.w), __fmul_rn(2.0f, dot));
      float dist = sqrtf(fmaxf(d2, 0.0f));           // IEEE sqrt, matches np
      if ((dist < RADIUS_F) && (m != 0u)) dens += 1.0f;
      u64 key = ((u64)__float_as_uint(dist) << 32) | (unsigned)(base + c);
      if (key < best[9]) insert10(best, key);
    }
    __syncthreads();
  }

  const int qf = b * N_PTS + q;
#pragma unroll
  for (int j = 0; j < 10; ++j)
    keysOut[(size_t)(s * 10 + j) * NQ_ALL + qf] = best[j];
  densOut[(size_t)s * NQ_ALL + qf] = dens;
}

// ---------------------------------------------------------------------------
// Kernel 2: merge segment top-10s, gather neighbors, covariance (f64),
// closed-form 3x3 symmetric eigenvalues, write geom[qf][6].
__global__ __launch_bounds__(256) void k_geom(const float* __restrict__ points,
                                              const u64* __restrict__ keys,
                                              const float* __restrict__ dens,
                                              const float* __restrict__ center,
                                              float* __restrict__ geom, int S) {
  const int qf = blockIdx.x * 256 + threadIdx.x;      // 0..NQ_ALL-1
  const int b = qf >> 13;
  const int q = qf & (N_PTS - 1);
  const float* P = points + (size_t)b * N_PTS * 3;

  u64 best[10];
#pragma unroll
  for (int j = 0; j < 10; ++j) best[j] = ~0ull;
  for (int s = 0; s < S; ++s) {
#pragma unroll
    for (int j = 0; j < 10; ++j) {
      u64 key = keys[(size_t)(s * 10 + j) * NQ_ALL + qf];
      if (key < best[9]) insert10(best, key);
    }
  }
  float density = 0.0f;
  for (int s = 0; s < S; ++s) density += dens[(size_t)s * NQ_ALL + qf];

  const float px = P[3 * q + 0];
  const float py = P[3 * q + 1];
  const float pz = P[3 * q + 2];

  double c00 = 0, c01 = 0, c02 = 0, c11 = 0, c12 = 0, c22 = 0;
#pragma unroll
  for (int j = 0; j < 10; ++j) {
    unsigned idx = (unsigned)best[j];                  // low 32 bits
    float nx = P[3 * idx + 0], ny = P[3 * idx + 1], nz = P[3 * idx + 2];
    float cx = __fsub_rn(nx, px);                      // centered, f32 like ref
    float cy = __fsub_rn(ny, py);
    float cz = __fsub_rn(nz, pz);
    c00 += (double)cx * cx; c01 += (double)cx * cy; c02 += (double)cx * cz;
    c11 += (double)cy * cy; c12 += (double)cy * cz; c22 += (double)cz * cz;
  }
  const double a00 = c00 / 10.0, a01 = c01 / 10.0, a02 = c02 / 10.0;
  const double a11 = c11 / 10.0, a12 = c12 / 10.0, a22 = c22 / 10.0;

  // closed-form symmetric 3x3 eigenvalues (ascending ev0 <= ev1 <= ev2)
  double p1 = a01 * a01 + a02 * a02 + a12 * a12;
  double qq = (a00 + a11 + a22) / 3.0;
  double p2 = (a00 - qq) * (a00 - qq) + (a11 - qq) * (a11 - qq) +
              (a22 - qq) * (a22 - qq) + 2.0 * p1;
  double ev0, ev2;
  if (p2 <= 1e-60) {
    ev0 = ev2 = qq;
  } else {
    double p = sqrt(p2 / 6.0);
    double invp = 1.0 / p;
    double b00 = (a00 - qq) * invp, b11 = (a11 - qq) * invp, b22 = (a22 - qq) * invp;
    double b01 = a01 * invp, b02 = a02 * invp, b12 = a12 * invp;
    double detB = b00 * (b11 * b22 - b12 * b12) - b01 * (b01 * b22 - b12 * b02) +
                  b02 * (b01 * b12 - b11 * b02);
    double r = 0.5 * detB;
    r = fmin(1.0, fmax(-1.0, r));
    double phi = acos(r) / 3.0;
    ev2 = qq + 2.0 * p * cos(phi);
    ev0 = qq + 2.0 * p * cos(phi + 2.0943951023931953);  // +2*pi/3
  }
  float curv = (float)(ev0 / (ev2 + 1e-08));

  const float4 ctr = reinterpret_cast<const float4*>(center)[b];
  const float flag = ctr.w;
  float rx = __fsub_rn(px, ctr.x);
  float ry = __fsub_rn(py, ctr.y);
  float rz = __fsub_rn(pz, ctr.z);
  float dist_c = sqrtf(sq3(rx, ry, rz));
  float horiz = sqrtf(__fadd_rn(__fmul_rn(rx, rx), __fmul_rn(ry, ry)));
  float rad = atan2f(ry, rx);

  float* g = geom + (size_t)qf * 6;
  const bool on = flag > 0.0f;
  g[0] = on ? dist_c : 0.0f;
  g[1] = on ? rz : 0.0f;
  g[2] = on ? horiz : 0.0f;
  g[3] = on ? density : 0.0f;
  g[4] = on ? curv : 0.0f;
  g[5] = on ? rad : 0.0f;
}

// ---------------------------------------------------------------------------
// Kernel 3: fused 2-layer MLP. Block = 256 threads, tile = 64 rows x 128 cols.
// A (combined 70-wide) and H (hidden) staged in LDS; W1/W2 streamed from
// global (L1-resident). Padded strides 74/130 keep the 4 per-thread row
// broadcasts on distinct banks.
__global__ __launch_bounds__(256) void k_mlp(const float* __restrict__ features,
                                             const float* __restrict__ geom,
                                             const float* __restrict__ W1,
                                             const float* __restrict__ b1,
                                             const float* __restrict__ W2,
                                             const float* __restrict__ b2,
                                             float* __restrict__ out) {
  __shared__ float A[64][74];
  __shared__ float H[64][130];
  const int tid = threadIdx.x;
  const int row0 = blockIdx.x * 64;

  for (int i = tid; i < 64 * IN_DIM; i += 256) {
    int r = i >> 6, k = i & 63;
    A[r][k] = features[(size_t)(row0 + r) * IN_DIM + k];
  }
  for (int i = tid; i < 64 * 8; i += 256) {
    int r = i >> 3, k = i & 7;
    if (k < 6) A[r][IN_DIM + k] = geom[(size_t)(row0 + r) * 6 + k];
  }
  __syncthreads();

  const int ty = tid >> 4;   // 0..15 -> rows ty*4 .. ty*4+3
  const int tx = tid & 15;   // cols tx*8 .. tx*8+7

  float acc[4][8];
#pragma unroll
  for (int i = 0; i < 4; ++i)
#pragma unroll
    for (int j = 0; j < 8; ++j) acc[i][j] = 0.0f;

#pragma unroll 2
  for (int k = 0; k < D_IN; ++k) {
    float a[4];
#pragma unroll
    for (int i = 0; i < 4; ++i) a[i] = A[ty * 4 + i][k];
    float4 w0 = *reinterpret_cast<const float4*>(&W1[(size_t)k * ODIM + tx * 8]);
    float4 w1 = *reinterpret_cast<const float4*>(&W1[(size_t)k * ODIM + tx * 8 + 4]);
    float w[8] = {w0.x, w0.y, w0.z, w0.w, w1.x, w1.y, w1.z, w1.w};
#pragma unroll
    for (int i = 0; i < 4; ++i)
#pragma unroll
      for (int j = 0; j < 8; ++j) acc[i][j] = fmaf(a[i], w[j], acc[i][j]);
  }

  {
    float4 bb0 = *reinterpret_cast<const float4*>(&b1[tx * 8]);
    float4 bb1 = *reinterpret_cast<const float4*>(&b1[tx * 8 + 4]);
    float bb[8] = {bb0.x, bb0.y, bb0.z, bb0.w, bb1.x, bb1.y, bb1.z, bb1.w};
#pragma unroll
    for (int i = 0; i < 4; ++i) {
      float4 h0 = make_float4(fmaxf(acc[i][0] + bb[0], 0.f), fmaxf(acc[i][1] + bb[1], 0.f),
                              fmaxf(acc[i][2] + bb[2], 0.f), fmaxf(acc[i][3] + bb[3], 0.f));
      float4 h1 = make_float4(fmaxf(acc[i][4] + bb[4], 0.f), fmaxf(acc[i][5] + bb[5], 0.f),
                              fmaxf(acc[i][6] + bb[6], 0.f), fmaxf(acc[i][7] + bb[7], 0.f));
      *reinterpret_cast<float4*>(&H[ty * 4 + i][tx * 8]) = h0;
      *reinterpret_cast<float4*>(&H[ty * 4 + i][tx * 8 + 4]) = h1;
    }
  }
  __syncthreads();

#pragma unroll
  for (int i = 0; i < 4; ++i)
#pragma unroll
    for (int j = 0; j < 8; ++j) acc[i][j] = 0.0f;

#pragma unroll 2
  for (int k = 0; k < ODIM; ++k) {
    float a[4];
#pragma unroll
    for (int i = 0; i < 4; ++i) a[i] = H[ty * 4 + i][k];
    float4 w0 = *reinterpret_cast<const float4*>(&W2[(size_t)k * ODIM + tx * 8]);
    float4 w1 = *reinterpret_cast<const float4*>(&W2[(size_t)k * ODIM + tx * 8 + 4]);
    float w[8] = {w0.x, w0.y, w0.z, w0.w, w1.x, w1.y, w1.z, w1.w};
#pragma unroll
    for (int i = 0; i < 4; ++i)
#pragma unroll
      for (int j = 0; j < 8; ++j) acc[i][j] = fmaf(a[i], w[j], acc[i][j]);
  }

  {
    float4 bb0 = *reinterpret_cast<const float4*>(&b2[tx * 8]);
    float4 bb1 = *reinterpret_cast<const float4*>(&b2[tx * 8 + 4]);
    float bb[8] = {bb0.x, bb0.y, bb0.z, bb0.w, bb1.x, bb1.y, bb1.z, bb1.w};
#pragma unroll
    for (int i = 0; i < 4; ++i) {
      size_t row = (size_t)(row0 + ty * 4 + i);
      float4 o0 = make_float4(fmaxf(acc[i][0] + bb[0], 0.f), fmaxf(acc[i][1] + bb[1], 0.f),
                              fmaxf(acc[i][2] + bb[2], 0.f), fmaxf(acc[i][3] + bb[3], 0.f));
      float4 o1 = make_float4(fmaxf(acc[i][4] + bb[4], 0.f), fmaxf(acc[i][5] + bb[5], 0.f),
                              fmaxf(acc[i][6] + bb[6], 0.f), fmaxf(acc[i][7] + bb[7], 0.f));
      *reinterpret_cast<float4*>(&out[row * ODIM + tx * 8]) = o0;
      *reinterpret_cast<float4*>(&out[row * ODIM + tx * 8 + 4]) = o1;
    }
  }
}

// ---------------------------------------------------------------------------
extern "C" void kernel_launch(void* const* d_in, const int* in_sizes, int n_in,
                              void* d_out, int out_size, void* d_ws, size_t ws_size,
                              hipStream_t stream) {
  const float* points   = (const float*)d_in[0];
  const float* features = (const float*)d_in[1];
  const int*   mask     = (const int*)d_in[2];
  const float* W1       = (const float*)d_in[3];
  const float* b1       = (const float*)d_in[4];
  const float* W2       = (const float*)d_in[5];
  const float* b2       = (const float*)d_in[6];
  float* out = (float*)d_out;

  // ws layout: [geom (NQ*6 f32)] [center (2*float4, 256B pad)] [keys (S*10*NQ u64)] [dens (S*NQ f32)]
  const size_t geomB = (size_t)NQ_ALL * 6 * 4;
  const size_t ctrB  = 256;
  int S = 16;
  while (S > 1) {
    size_t need = geomB + ctrB + (size_t)S * 10 * NQ_ALL * 8 + (size_t)S * NQ_ALL * 4;
    if (need <= ws_size) break;
    S >>= 1;
  }
  const int L = N_PTS / S;

  char* w = (char*)d_ws;
  float* geomBuf   = (float*)w;
  float* centerBuf = (float*)(w + geomB);
  u64*   keysBuf   = (u64*)(w + geomB + ctrB);
  float* densBuf   = (float*)(w + geomB + ctrB + (size_t)S * 10 * NQ_ALL * 8);

  k_center<<<B_SZ, 256, 0, stream>>>(points, mask, centerBuf);
  k_pairwise<<<dim3(N_PTS / 256, S, B_SZ), 256, 0, stream>>>(points, mask, keysBuf, densBuf, S, L);
  k_geom<<<NQ_ALL / 256, 256, 0, stream>>>(points, keysBuf, densBuf, centerBuf, geomBuf, S);
  k_mlp<<<NQ_ALL / 64, 256, 0, stream>>>(features, geomBuf, W1, b1, W2, b2, out);
}

// Round 2
// 273.550 us; speedup vs baseline: 1.8765x; 1.8765x over previous
//
#include <hip/hip_runtime.h>
#include <math.h>
#include <stdint.h>

#define B_SZ   2
#define N_PTS  8192
#define IN_DIM 64
#define D_IN   70          // 64 features + 6 geom
#define ODIM   128
#define NQ_ALL (B_SZ * N_PTS)
#define RADIUS_F 0.02f

#define GDIM  16
#define NCELL (GDIM * GDIM * GDIM)
#define HCELL 0.0625f      // 1/16, exact in f32

typedef unsigned long long u64;

// ---------------------------------------------------------------------------
// sorted top-10 (ascending) insert via unrolled min/max chain (registers only)
__device__ __forceinline__ void insert10(u64 (&best)[10], u64 key) {
#pragma unroll
  for (int j = 9; j >= 1; --j) {
    u64 hi = (best[j - 1] > key) ? best[j - 1] : key;
    best[j] = (best[j] < hi) ? best[j] : hi;
  }
  best[0] = (best[0] < key) ? best[0] : key;
}

// exact f32 helpers matching the reference's op order (no contraction)
__device__ __forceinline__ float sq3(float x, float y, float z) {
  return __fadd_rn(__fadd_rn(__fmul_rn(x, x), __fmul_rn(y, y)), __fmul_rn(z, z));
}

__device__ __forceinline__ int cellOf(float v) {
  int c = (int)(v * 16.0f);
  return min(max(c, 0), GDIM - 1);
}

// ---------------------------------------------------------------------------
// Kernel 0: per-batch masked centroid (f64 reduce -> f32 like ref)
__global__ __launch_bounds__(256) void k_center(const float* __restrict__ points,
                                                const int* __restrict__ mask,
                                                float* __restrict__ centerOut) {
  const int b = blockIdx.x;
  const float* P = points + (size_t)b * N_PTS * 3;
  const int* M = mask + (size_t)b * N_PTS;
  double sx = 0.0, sy = 0.0, sz = 0.0, sc = 0.0;
  for (int i = threadIdx.x; i < N_PTS; i += 256) {
    if (M[i] != 0) {
      sx += (double)P[3 * i + 0];
      sy += (double)P[3 * i + 1];
      sz += (double)P[3 * i + 2];
      sc += 1.0;
    }
  }
  __shared__ double sh[4][256];
  sh[0][threadIdx.x] = sx; sh[1][threadIdx.x] = sy;
  sh[2][threadIdx.x] = sz; sh[3][threadIdx.x] = sc;
  __syncthreads();
  for (int off = 128; off > 0; off >>= 1) {
    if ((int)threadIdx.x < off) {
      sh[0][threadIdx.x] += sh[0][threadIdx.x + off];
      sh[1][threadIdx.x] += sh[1][threadIdx.x + off];
      sh[2][threadIdx.x] += sh[2][threadIdx.x + off];
      sh[3][threadIdx.x] += sh[3][threadIdx.x + off];
    }
    __syncthreads();
  }
  if (threadIdx.x == 0) {
    float cf  = (float)sh[3][0];
    float div = fmaxf(cf, 1.0f);
    centerOut[b * 4 + 0] = (float)sh[0][0] / div;
    centerOut[b * 4 + 1] = (float)sh[1][0] / div;
    centerOut[b * 4 + 2] = (float)sh[2][0] / div;
    centerOut[b * 4 + 3] = (cf > 0.0f) ? 1.0f : 0.0f;   // mask-nonempty flag
  }
}

// ---------------------------------------------------------------------------
// Grid build: count -> scan -> scatter
__global__ __launch_bounds__(256) void k_grid_count(const float* __restrict__ points,
                                                    int* __restrict__ count) {
  const int t = blockIdx.x * 256 + threadIdx.x;   // 0..NQ_ALL-1
  const int b = t >> 13;
  const int i = t & (N_PTS - 1);
  const float* P = points + (size_t)b * N_PTS * 3;
  const int cx = cellOf(P[3 * i + 0]);
  const int cy = cellOf(P[3 * i + 1]);
  const int cz = cellOf(P[3 * i + 2]);
  atomicAdd(&count[b * NCELL + (cz * GDIM + cy) * GDIM + cx], 1);
}

// one block of 1024 threads per batch; exclusive scan of 4096 counts
__global__ __launch_bounds__(1024) void k_scan(const int* __restrict__ count,
                                               int* __restrict__ start,
                                               int* __restrict__ cur) {
  const int b = blockIdx.x;
  const int t = threadIdx.x;
  int c[4]; int sum = 0;
#pragma unroll
  for (int j = 0; j < 4; ++j) { c[j] = count[b * NCELL + t * 4 + j]; sum += c[j]; }
  __shared__ int s[1024];
  s[t] = sum;
  __syncthreads();
  for (int off = 1; off < 1024; off <<= 1) {
    int v = (t >= off) ? s[t - off] : 0;
    __syncthreads();
    if (t >= off) s[t] += v;
    __syncthreads();
  }
  int excl = (t > 0) ? s[t - 1] : 0;
#pragma unroll
  for (int j = 0; j < 4; ++j) {
    start[b * (NCELL + 1) + t * 4 + j] = excl;
    cur[b * NCELL + t * 4 + j] = excl;
    excl += c[j];
  }
  if (t == 1023) start[b * (NCELL + 1) + NCELL] = excl;
}

__global__ __launch_bounds__(256) void k_scatter(const float* __restrict__ points,
                                                 const int* __restrict__ mask,
                                                 int* __restrict__ cur,
                                                 float4* __restrict__ sorted) {
  const int t = blockIdx.x * 256 + threadIdx.x;
  const int b = t >> 13;
  const int i = t & (N_PTS - 1);
  const float* P = points + (size_t)b * N_PTS * 3;
  const float x = P[3 * i + 0], y = P[3 * i + 1], z = P[3 * i + 2];
  const int cell = (cellOf(z) * GDIM + cellOf(y)) * GDIM + cellOf(x);
  const int pos = atomicAdd(&cur[b * NCELL + cell], 1);
  const unsigned wb = (unsigned)i | ((mask[b * N_PTS + i] != 0) ? 0x80000000u : 0u);
  sorted[(size_t)b * N_PTS + pos] = make_float4(x, y, z, __uint_as_float(wb));
}

// ---------------------------------------------------------------------------
// Kernel Q: per-query grid ring scan -> exact top-10 + density, then
// covariance (f64) + closed-form eigenvalues + geometry write.
__global__ __launch_bounds__(256) void k_query(const float* __restrict__ points,
                                               const float4* __restrict__ sorted,
                                               const int* __restrict__ start,
                                               const float* __restrict__ center,
                                               float* __restrict__ geom) {
  const int b = blockIdx.y;
  const int qs = blockIdx.x * 256 + threadIdx.x;   // sorted position
  const float4 qp = sorted[(size_t)b * N_PTS + qs];
  const unsigned qw = __float_as_uint(qp.w);
  const int qidx = (int)(qw & 0x7FFFFFFFu);

  const float px = qp.x, py = qp.y, pz = qp.z;
  const float sqq = sq3(px, py, pz);
  const int cx = cellOf(px), cy = cellOf(py), cz = cellOf(pz);

  const int* ST = start + b * (NCELL + 1);
  const float4* SP = sorted + (size_t)b * N_PTS;

  u64 best[10];
#pragma unroll
  for (int j = 0; j < 10; ++j) best[j] = ((u64)0x7F800000u << 32) | 0xFFFFFFFFu; // +inf dist
  float dens = 0.0f;

  for (int rho = 0; rho < GDIM; ++rho) {
    const int zlo = max(cz - rho, 0), zhi = min(cz + rho, GDIM - 1);
    const int ylo = max(cy - rho, 0), yhi = min(cy + rho, GDIM - 1);
    for (int z = zlo; z <= zhi; ++z) {
      const int adz = abs(z - cz);
      for (int y = ylo; y <= yhi; ++y) {
        const int ady = abs(y - cy);
        const int m2 = max(adz, ady);
        int ja, jb;            // candidate ranges (up to two)
        int ja2 = 0, jb2 = 0;  // second single-cell run
        const int rowBase = (z * GDIM + y) * GDIM;
        if (m2 == rho) {
          const int xa = max(cx - rho, 0), xb = min(cx + rho, GDIM - 1);
          ja = ST[rowBase + xa]; jb = ST[rowBase + xb + 1];
        } else {
          ja = jb = 0;
          if (cx - rho >= 0)       { ja = ST[rowBase + cx - rho]; jb = ST[rowBase + cx - rho + 1]; }
          if (cx + rho <= GDIM - 1){ ja2 = ST[rowBase + cx + rho]; jb2 = ST[rowBase + cx + rho + 1]; }
        }
#pragma unroll 1
        for (int pass = 0; pass < 2; ++pass) {
          const int j0 = pass ? ja2 : ja;
          const int j1 = pass ? jb2 : jb;
          for (int j = j0; j < j1; ++j) {
            const float4 tp = SP[j];
            const unsigned wb = __float_as_uint(tp.w);
            const float sqc = sq3(tp.x, tp.y, tp.z);
            // reference order: dot = fma(z,.,fma(y,.,x*x)); d2 = (sqi+sqj) - 2*dot
            const float dot = __fmaf_rn(pz, tp.z, __fmaf_rn(py, tp.y, __fmul_rn(px, tp.x)));
            const float d2  = __fsub_rn(__fadd_rn(sqq, sqc), __fmul_rn(2.0f, dot));
            const float dist = sqrtf(fmaxf(d2, 0.0f));
            if ((dist < RADIUS_F) && (wb & 0x80000000u)) dens += 1.0f;
            const u64 key = ((u64)__float_as_uint(dist) << 32) | (wb & 0x7FFFFFFFu);
            if (key < best[9]) insert10(best, key);
          }
        }
      }
    }
    if (rho >= 1) {
      const float dist9 = __uint_as_float((unsigned)(best[9] >> 32));
      if (dist9 < (float)rho * HCELL * 0.999f) break;   // all unscanned strictly farther
    }
  }

  // ---- covariance over the 10 NN (ascending key order, matches ref) ----
  const float* P = points + (size_t)b * N_PTS * 3;
  double c00 = 0, c01 = 0, c02 = 0, c11 = 0, c12 = 0, c22 = 0;
#pragma unroll
  for (int j = 0; j < 10; ++j) {
    const unsigned idx = (unsigned)best[j];            // low 32 bits = orig index
    const float nx = P[3 * idx + 0], ny = P[3 * idx + 1], nz = P[3 * idx + 2];
    const float ex = __fsub_rn(nx, px);
    const float ey = __fsub_rn(ny, py);
    const float ez = __fsub_rn(nz, pz);
    c00 += (double)ex * ex; c01 += (double)ex * ey; c02 += (double)ex * ez;
    c11 += (double)ey * ey; c12 += (double)ey * ez; c22 += (double)ez * ez;
  }
  const double a00 = c00 / 10.0, a01 = c01 / 10.0, a02 = c02 / 10.0;
  const double a11 = c11 / 10.0, a12 = c12 / 10.0, a22 = c22 / 10.0;

  double p1 = a01 * a01 + a02 * a02 + a12 * a12;
  double qq = (a00 + a11 + a22) / 3.0;
  double p2 = (a00 - qq) * (a00 - qq) + (a11 - qq) * (a11 - qq) +
              (a22 - qq) * (a22 - qq) + 2.0 * p1;
  double ev0, ev2;
  if (p2 <= 1e-60) {
    ev0 = ev2 = qq;
  } else {
    double p = sqrt(p2 / 6.0);
    double invp = 1.0 / p;
    double b00 = (a00 - qq) * invp, b11 = (a11 - qq) * invp, b22 = (a22 - qq) * invp;
    double b01 = a01 * invp, b02 = a02 * invp, b12 = a12 * invp;
    double detB = b00 * (b11 * b22 - b12 * b12) - b01 * (b01 * b22 - b12 * b02) +
                  b02 * (b01 * b12 - b11 * b02);
    double r = 0.5 * detB;
    r = fmin(1.0, fmax(-1.0, r));
    double phi = acos(r) / 3.0;
    ev2 = qq + 2.0 * p * cos(phi);
    ev0 = qq + 2.0 * p * cos(phi + 2.0943951023931953);  // +2*pi/3
  }
  const float curv = (float)(ev0 / (ev2 + 1e-08));

  const float4 ctr = reinterpret_cast<const float4*>(center)[b];
  const bool on = ctr.w > 0.0f;
  const float rx = __fsub_rn(px, ctr.x);
  const float ry = __fsub_rn(py, ctr.y);
  const float rz = __fsub_rn(pz, ctr.z);
  const float dist_c = sqrtf(sq3(rx, ry, rz));
  const float horiz  = sqrtf(__fadd_rn(__fmul_rn(rx, rx), __fmul_rn(ry, ry)));
  const float rad    = atan2f(ry, rx);

  float* g = geom + ((size_t)b * N_PTS + qidx) * 6;
  g[0] = on ? dist_c : 0.0f;
  g[1] = on ? rz : 0.0f;
  g[2] = on ? horiz : 0.0f;
  g[3] = on ? dens : 0.0f;
  g[4] = on ? curv : 0.0f;
  g[5] = on ? rad : 0.0f;
}

// ---------------------------------------------------------------------------
// Kernel 3: fused 2-layer MLP (unchanged from R1).
__global__ __launch_bounds__(256) void k_mlp(const float* __restrict__ features,
                                             const float* __restrict__ geom,
                                             const float* __restrict__ W1,
                                             const float* __restrict__ b1,
                                             const float* __restrict__ W2,
                                             const float* __restrict__ b2,
                                             float* __restrict__ out) {
  __shared__ float A[64][74];
  __shared__ float H[64][130];
  const int tid = threadIdx.x;
  const int row0 = blockIdx.x * 64;

  for (int i = tid; i < 64 * IN_DIM; i += 256) {
    int r = i >> 6, k = i & 63;
    A[r][k] = features[(size_t)(row0 + r) * IN_DIM + k];
  }
  for (int i = tid; i < 64 * 8; i += 256) {
    int r = i >> 3, k = i & 7;
    if (k < 6) A[r][IN_DIM + k] = geom[(size_t)(row0 + r) * 6 + k];
  }
  __syncthreads();

  const int ty = tid >> 4;
  const int tx = tid & 15;

  float acc[4][8];
#pragma unroll
  for (int i = 0; i < 4; ++i)
#pragma unroll
    for (int j = 0; j < 8; ++j) acc[i][j] = 0.0f;

#pragma unroll 2
  for (int k = 0; k < D_IN; ++k) {
    float a[4];
#pragma unroll
    for (int i = 0; i < 4; ++i) a[i] = A[ty * 4 + i][k];
    float4 w0 = *reinterpret_cast<const float4*>(&W1[(size_t)k * ODIM + tx * 8]);
    float4 w1 = *reinterpret_cast<const float4*>(&W1[(size_t)k * ODIM + tx * 8 + 4]);
    float w[8] = {w0.x, w0.y, w0.z, w0.w, w1.x, w1.y, w1.z, w1.w};
#pragma unroll
    for (int i = 0; i < 4; ++i)
#pragma unroll
      for (int j = 0; j < 8; ++j) acc[i][j] = fmaf(a[i], w[j], acc[i][j]);
  }

  {
    float4 bb0 = *reinterpret_cast<const float4*>(&b1[tx * 8]);
    float4 bb1 = *reinterpret_cast<const float4*>(&b1[tx * 8 + 4]);
    float bb[8] = {bb0.x, bb0.y, bb0.z, bb0.w, bb1.x, bb1.y, bb1.z, bb1.w};
#pragma unroll
    for (int i = 0; i < 4; ++i) {
      float4 h0 = make_float4(fmaxf(acc[i][0] + bb[0], 0.f), fmaxf(acc[i][1] + bb[1], 0.f),
                              fmaxf(acc[i][2] + bb[2], 0.f), fmaxf(acc[i][3] + bb[3], 0.f));
      float4 h1 = make_float4(fmaxf(acc[i][4] + bb[4], 0.f), fmaxf(acc[i][5] + bb[5], 0.f),
                              fmaxf(acc[i][6] + bb[6], 0.f), fmaxf(acc[i][7] + bb[7], 0.f));
      *reinterpret_cast<float4*>(&H[ty * 4 + i][tx * 8]) = h0;
      *reinterpret_cast<float4*>(&H[ty * 4 + i][tx * 8 + 4]) = h1;
    }
  }
  __syncthreads();

#pragma unroll
  for (int i = 0; i < 4; ++i)
#pragma unroll
    for (int j = 0; j < 8; ++j) acc[i][j] = 0.0f;

#pragma unroll 2
  for (int k = 0; k < ODIM; ++k) {
    float a[4];
#pragma unroll
    for (int i = 0; i < 4; ++i) a[i] = H[ty * 4 + i][k];
    float4 w0 = *reinterpret_cast<const float4*>(&W2[(size_t)k * ODIM + tx * 8]);
    float4 w1 = *reinterpret_cast<const float4*>(&W2[(size_t)k * ODIM + tx * 8 + 4]);
    float w[8] = {w0.x, w0.y, w0.z, w0.w, w1.x, w1.y, w1.z, w1.w};
#pragma unroll
    for (int i = 0; i < 4; ++i)
#pragma unroll
      for (int j = 0; j < 8; ++j) acc[i][j] = fmaf(a[i], w[j], acc[i][j]);
  }

  {
    float4 bb0 = *reinterpret_cast<const float4*>(&b2[tx * 8]);
    float4 bb1 = *reinterpret_cast<const float4*>(&b2[tx * 8 + 4]);
    float bb[8] = {bb0.x, bb0.y, bb0.z, bb0.w, bb1.x, bb1.y, bb1.z, bb1.w};
#pragma unroll
    for (int i = 0; i < 4; ++i) {
      size_t row = (size_t)(row0 + ty * 4 + i);
      float4 o0 = make_float4(fmaxf(acc[i][0] + bb[0], 0.f), fmaxf(acc[i][1] + bb[1], 0.f),
                              fmaxf(acc[i][2] + bb[2], 0.f), fmaxf(acc[i][3] + bb[3], 0.f));
      float4 o1 = make_float4(fmaxf(acc[i][4] + bb[4], 0.f), fmaxf(acc[i][5] + bb[5], 0.f),
                              fmaxf(acc[i][6] + bb[6], 0.f), fmaxf(acc[i][7] + bb[7], 0.f));
      *reinterpret_cast<float4*>(&out[row * ODIM + tx * 8]) = o0;
      *reinterpret_cast<float4*>(&out[row * ODIM + tx * 8 + 4]) = o1;
    }
  }
}

// ---------------------------------------------------------------------------
extern "C" void kernel_launch(void* const* d_in, const int* in_sizes, int n_in,
                              void* d_out, int out_size, void* d_ws, size_t ws_size,
                              hipStream_t stream) {
  const float* points   = (const float*)d_in[0];
  const float* features = (const float*)d_in[1];
  const int*   mask     = (const int*)d_in[2];
  const float* W1       = (const float*)d_in[3];
  const float* b1       = (const float*)d_in[4];
  const float* W2       = (const float*)d_in[5];
  const float* b2       = (const float*)d_in[6];
  float* out = (float*)d_out;

  // ws layout (all 256B aligned):
  char* w = (char*)d_ws;
  size_t off = 0;
  auto take = [&](size_t bytes) { char* p = w + off; off = (off + bytes + 255) & ~(size_t)255; return p; };
  float*  geomBuf   = (float*)take((size_t)NQ_ALL * 6 * 4);
  float*  centerBuf = (float*)take(2 * 16);
  int*    countBuf  = (int*)take((size_t)B_SZ * NCELL * 4);
  int*    startBuf  = (int*)take((size_t)B_SZ * (NCELL + 1) * 4);
  int*    curBuf    = (int*)take((size_t)B_SZ * NCELL * 4);
  float4* sortedBuf = (float4*)take((size_t)B_SZ * N_PTS * 16);
  (void)ws_size;

  hipMemsetAsync(countBuf, 0, (size_t)B_SZ * NCELL * 4, stream);
  k_center<<<B_SZ, 256, 0, stream>>>(points, mask, centerBuf);
  k_grid_count<<<NQ_ALL / 256, 256, 0, stream>>>(points, countBuf);
  k_scan<<<B_SZ, 1024, 0, stream>>>(countBuf, startBuf, curBuf);
  k_scatter<<<NQ_ALL / 256, 256, 0, stream>>>(points, mask, curBuf, sortedBuf);
  k_query<<<dim3(N_PTS / 256, B_SZ), 256, 0, stream>>>(points, sortedBuf, startBuf, centerBuf, geomBuf);
  k_mlp<<<NQ_ALL / 64, 256, 0, stream>>>(features, geomBuf, W1, b1, W2, b2, out);
}

// Round 3
// 215.438 us; speedup vs baseline: 2.3827x; 1.2697x over previous
//
#include <hip/hip_runtime.h>
#include <math.h>
#include <stdint.h>

#define B_SZ   2
#define N_PTS  8192
#define IN_DIM 64
#define D_IN   70          // 64 features + 6 geom
#define ODIM   128
#define NQ_ALL (B_SZ * N_PTS)
#define RADIUS_F 0.02f

#define GDIM  16
#define NCELL (GDIM * GDIM * GDIM)
#define HCELL 0.0625f      // 1/16, exact in f32

#define SDIM  8            // supercells per axis (2x2x2 base cells each)
#define NSUPER (SDIM * SDIM * SDIM)
#define SCAP  1024         // staged-halo capacity (points)

typedef unsigned long long u64;

// ---------------------------------------------------------------------------
// sorted top-10 (ascending) insert via unrolled min/max chain (registers only)
__device__ __forceinline__ void insert10(u64 (&best)[10], u64 key) {
#pragma unroll
  for (int j = 9; j >= 1; --j) {
    u64 hi = (best[j - 1] > key) ? best[j - 1] : key;
    best[j] = (best[j] < hi) ? best[j] : hi;
  }
  best[0] = (best[0] < key) ? best[0] : key;
}

// exact f32 helpers matching the reference's op order (no contraction)
__device__ __forceinline__ float sq3(float x, float y, float z) {
  return __fadd_rn(__fadd_rn(__fmul_rn(x, x), __fmul_rn(y, y)), __fmul_rn(z, z));
}

__device__ __forceinline__ int cellOf(float v) {
  int c = (int)(v * 16.0f);
  return min(max(c, 0), GDIM - 1);
}

// shared epilogue: covariance over the 10 NN (exact R2 math) + eigen + geom
__device__ __forceinline__ void geom_epilogue(const float* __restrict__ P,
                                              const u64 (&best)[10], float dens,
                                              float px, float py, float pz,
                                              float4 ctr, float* __restrict__ g) {
  double c00 = 0, c01 = 0, c02 = 0, c11 = 0, c12 = 0, c22 = 0;
#pragma unroll
  for (int j = 0; j < 10; ++j) {
    const unsigned idx = (unsigned)best[j];            // low 32 bits = orig index
    const float nx = P[3 * idx + 0], ny = P[3 * idx + 1], nz = P[3 * idx + 2];
    const float ex = __fsub_rn(nx, px);
    const float ey = __fsub_rn(ny, py);
    const float ez = __fsub_rn(nz, pz);
    c00 += (double)ex * ex; c01 += (double)ex * ey; c02 += (double)ex * ez;
    c11 += (double)ey * ey; c12 += (double)ey * ez; c22 += (double)ez * ez;
  }
  const double a00 = c00 / 10.0, a01 = c01 / 10.0, a02 = c02 / 10.0;
  const double a11 = c11 / 10.0, a12 = c12 / 10.0, a22 = c22 / 10.0;

  double p1 = a01 * a01 + a02 * a02 + a12 * a12;
  double qq = (a00 + a11 + a22) / 3.0;
  double p2 = (a00 - qq) * (a00 - qq) + (a11 - qq) * (a11 - qq) +
              (a22 - qq) * (a22 - qq) + 2.0 * p1;
  double ev0, ev2;
  if (p2 <= 1e-60) {
    ev0 = ev2 = qq;
  } else {
    double p = sqrt(p2 / 6.0);
    double invp = 1.0 / p;
    double b00 = (a00 - qq) * invp, b11 = (a11 - qq) * invp, b22 = (a22 - qq) * invp;
    double b01 = a01 * invp, b02 = a02 * invp, b12 = a12 * invp;
    double detB = b00 * (b11 * b22 - b12 * b12) - b01 * (b01 * b22 - b12 * b02) +
                  b02 * (b01 * b12 - b11 * b02);
    double r = 0.5 * detB;
    r = fmin(1.0, fmax(-1.0, r));
    double phi = acos(r) / 3.0;
    ev2 = qq + 2.0 * p * cos(phi);
    ev0 = qq + 2.0 * p * cos(phi + 2.0943951023931953);  // +2*pi/3
  }
  const float curv = (float)(ev0 / (ev2 + 1e-08));

  const bool on = ctr.w > 0.0f;
  const float rx = __fsub_rn(px, ctr.x);
  const float ry = __fsub_rn(py, ctr.y);
  const float rz = __fsub_rn(pz, ctr.z);
  const float dist_c = sqrtf(sq3(rx, ry, rz));
  const float horiz  = sqrtf(__fadd_rn(__fmul_rn(rx, rx), __fmul_rn(ry, ry)));
  const float rad    = atan2f(ry, rx);

  g[0] = on ? dist_c : 0.0f;
  g[1] = on ? rz : 0.0f;
  g[2] = on ? horiz : 0.0f;
  g[3] = on ? dens : 0.0f;
  g[4] = on ? curv : 0.0f;
  g[5] = on ? rad : 0.0f;
}

// ---------------------------------------------------------------------------
// Kernel 0: per-batch masked centroid (f64 reduce -> f32 like ref)
__global__ __launch_bounds__(256) void k_center(const float* __restrict__ points,
                                                const int* __restrict__ mask,
                                                float* __restrict__ centerOut) {
  const int b = blockIdx.x;
  const float* P = points + (size_t)b * N_PTS * 3;
  const int* M = mask + (size_t)b * N_PTS;
  double sx = 0.0, sy = 0.0, sz = 0.0, sc = 0.0;
  for (int i = threadIdx.x; i < N_PTS; i += 256) {
    if (M[i] != 0) {
      sx += (double)P[3 * i + 0];
      sy += (double)P[3 * i + 1];
      sz += (double)P[3 * i + 2];
      sc += 1.0;
    }
  }
  __shared__ double sh[4][256];
  sh[0][threadIdx.x] = sx; sh[1][threadIdx.x] = sy;
  sh[2][threadIdx.x] = sz; sh[3][threadIdx.x] = sc;
  __syncthreads();
  for (int off = 128; off > 0; off >>= 1) {
    if ((int)threadIdx.x < off) {
      sh[0][threadIdx.x] += sh[0][threadIdx.x + off];
      sh[1][threadIdx.x] += sh[1][threadIdx.x + off];
      sh[2][threadIdx.x] += sh[2][threadIdx.x + off];
      sh[3][threadIdx.x] += sh[3][threadIdx.x + off];
    }
    __syncthreads();
  }
  if (threadIdx.x == 0) {
    float cf  = (float)sh[3][0];
    float div = fmaxf(cf, 1.0f);
    centerOut[b * 4 + 0] = (float)sh[0][0] / div;
    centerOut[b * 4 + 1] = (float)sh[1][0] / div;
    centerOut[b * 4 + 2] = (float)sh[2][0] / div;
    centerOut[b * 4 + 3] = (cf > 0.0f) ? 1.0f : 0.0f;   // mask-nonempty flag
  }
}

// ---------------------------------------------------------------------------
// Grid build: count -> scan -> scatter
__global__ __launch_bounds__(256) void k_grid_count(const float* __restrict__ points,
                                                    int* __restrict__ count) {
  const int t = blockIdx.x * 256 + threadIdx.x;   // 0..NQ_ALL-1
  const int b = t >> 13;
  const int i = t & (N_PTS - 1);
  const float* P = points + (size_t)b * N_PTS * 3;
  const int cx = cellOf(P[3 * i + 0]);
  const int cy = cellOf(P[3 * i + 1]);
  const int cz = cellOf(P[3 * i + 2]);
  atomicAdd(&count[b * NCELL + (cz * GDIM + cy) * GDIM + cx], 1);
}

// one block of 1024 threads per batch; exclusive scan of 4096 counts
__global__ __launch_bounds__(1024) void k_scan(const int* __restrict__ count,
                                               int* __restrict__ start,
                                               int* __restrict__ cur) {
  const int b = blockIdx.x;
  const int t = threadIdx.x;
  int c[4]; int sum = 0;
#pragma unroll
  for (int j = 0; j < 4; ++j) { c[j] = count[b * NCELL + t * 4 + j]; sum += c[j]; }
  __shared__ int s[1024];
  s[t] = sum;
  __syncthreads();
  for (int off = 1; off < 1024; off <<= 1) {
    int v = (t >= off) ? s[t - off] : 0;
    __syncthreads();
    if (t >= off) s[t] += v;
    __syncthreads();
  }
  int excl = (t > 0) ? s[t - 1] : 0;
#pragma unroll
  for (int j = 0; j < 4; ++j) {
    start[b * (NCELL + 1) + t * 4 + j] = excl;
    cur[b * NCELL + t * 4 + j] = excl;
    excl += c[j];
  }
  if (t == 1023) start[b * (NCELL + 1) + NCELL] = excl;
}

__global__ __launch_bounds__(256) void k_scatter(const float* __restrict__ points,
                                                 const int* __restrict__ mask,
                                                 int* __restrict__ cur,
                                                 float4* __restrict__ sorted) {
  const int t = blockIdx.x * 256 + threadIdx.x;
  const int b = t >> 13;
  const int i = t & (N_PTS - 1);
  const float* P = points + (size_t)b * N_PTS * 3;
  const float x = P[3 * i + 0], y = P[3 * i + 1], z = P[3 * i + 2];
  const int cell = (cellOf(z) * GDIM + cellOf(y)) * GDIM + cellOf(x);
  const int pos = atomicAdd(&cur[b * NCELL + cell], 1);
  const unsigned wb = (unsigned)i | ((mask[b * N_PTS + i] != 0) ? 0x80000000u : 0u);
  sorted[(size_t)b * N_PTS + pos] = make_float4(x, y, z, __uint_as_float(wb));
}

// ---------------------------------------------------------------------------
// Kernel Q: supercell-cooperative query. One 256-thread block per supercell
// (2x2x2 base cells). Stage the +-2-base-cell halo into LDS, then 16 lanes
// per query scan the staged list; butterfly shfl_xor merge of top-10s.
__global__ __launch_bounds__(256) void k_qsuper(const float* __restrict__ points,
                                                const float4* __restrict__ sorted,
                                                const int* __restrict__ start,
                                                const float* __restrict__ center,
                                                float* __restrict__ geom,
                                                int* __restrict__ flags) {
  const int b  = blockIdx.y;
  const int sc = blockIdx.x;
  const int sx = sc & 7, sy = (sc >> 3) & 7, sz = sc >> 6;
  const int tid = threadIdx.x;

  const int* ST = start + b * (NCELL + 1);
  const float4* SP = sorted + (size_t)b * N_PTS;

  const int xlo = max(2 * sx - 2, 0), xhi = min(2 * sx + 3, GDIM - 1);
  const int ylo = max(2 * sy - 2, 0), yhi = min(2 * sy + 3, GDIM - 1);
  const int zlo = max(2 * sz - 2, 0), zhi = min(2 * sz + 3, GDIM - 1);
  const int ycnt = yhi - ylo + 1;
  const int zcnt = zhi - zlo + 1;
  const int R = zcnt * ycnt;                  // halo (z,y) rows, <= 36

  __shared__ float4 pts[SCAP];
  __shared__ int runStart[36], lenArr[36], runPre[37];
  __shared__ int qRunStart[4], qRunPre[5], qGlob[4], qLen[4];

  if (tid < R) {
    const int z = zlo + tid / ycnt;
    const int y = ylo + tid % ycnt;
    const int rowBase = (z * GDIM + y) * GDIM;
    const int s0 = ST[rowBase + xlo];
    const int s1 = ST[rowBase + xhi + 1];
    runStart[tid] = s0;
    lenArr[tid] = s1 - s0;
  }
  __syncthreads();
  if (tid == 0) {
    int acc = 0;
    for (int r = 0; r < R; ++r) { runPre[r] = acc; acc += lenArr[r]; }
    runPre[R] = acc;
    int qacc = 0;
    qRunPre[0] = 0;
#pragma unroll
    for (int k = 0; k < 4; ++k) {
      const int dz = k >> 1, dy = k & 1;
      const int z = 2 * sz + dz, y = 2 * sy + dy;
      const int r = (z - zlo) * ycnt + (y - ylo);
      const int rowBase = (z * GDIM + y) * GDIM;
      const int qs0 = ST[rowBase + 2 * sx];
      const int ql = ST[rowBase + 2 * sx + 2] - qs0;
      qGlob[k] = qs0;
      qLen[k] = ql;
      qRunStart[k] = runPre[r] + (qs0 - runStart[r]);
      qacc += ql;
      qRunPre[k + 1] = qacc;
    }
  }
  __syncthreads();

  const int C  = runPre[R];
  const int nq = qRunPre[4];
  if (nq == 0) return;

  if (C > SCAP) {                       // overflow: flag all queries, fallback handles
    for (int t = tid; t < nq; t += 256) {
      int k = 0;
      while (k < 3 && t >= qRunPre[k + 1]) ++k;
      const int j = qGlob[k] + (t - qRunPre[k]);
      const unsigned qw = __float_as_uint(SP[j].w);
      flags[b * N_PTS + (int)(qw & 0x7FFFFFFFu)] = 1;
    }
    return;
  }

  for (int i = tid; i < C; i += 256) {  // stage halo
    int lo = 0, hi = R - 1;
    while (lo < hi) { const int mid = (lo + hi + 1) >> 1; if (runPre[mid] <= i) lo = mid; else hi = mid - 1; }
    pts[i] = SP[runStart[lo] + (i - runPre[lo])];
  }
  __syncthreads();

  const float4 ctr = reinterpret_cast<const float4*>(center)[b];
  const float* P = points + (size_t)b * N_PTS * 3;
  const int sub = tid & 15;
  const int npass = (nq + 15) >> 4;

  for (int pass = 0; pass < npass; ++pass) {
    const int q = pass * 16 + (tid >> 4);
    const bool active = (q < nq);
    const int qc = active ? q : 0;
    int k = 0;
    while (k < 3 && qc >= qRunPre[k + 1]) ++k;
    const int qlds = qRunStart[k] + (qc - qRunPre[k]);
    const float4 qp = pts[qlds];
    const int qidx = (int)(__float_as_uint(qp.w) & 0x7FFFFFFFu);
    const float px = qp.x, py = qp.y, pz = qp.z;
    const float sqq = sq3(px, py, pz);

    u64 best[10];
#pragma unroll
    for (int j = 0; j < 10; ++j) best[j] = ((u64)0x7F800000u << 32) | 0xFFFFFFFFu;
    float dens = 0.0f;

    for (int j = sub; j < C; j += 16) {
      const float4 tp = pts[j];
      const unsigned wb = __float_as_uint(tp.w);
      const float sqc = sq3(tp.x, tp.y, tp.z);
      const float dot = __fmaf_rn(pz, tp.z, __fmaf_rn(py, tp.y, __fmul_rn(px, tp.x)));
      const float d2  = __fsub_rn(__fadd_rn(sqq, sqc), __fmul_rn(2.0f, dot));
      const float dist = sqrtf(fmaxf(d2, 0.0f));
      if ((dist < RADIUS_F) && (wb & 0x80000000u)) dens += 1.0f;
      const u64 key = ((u64)__float_as_uint(dist) << 32) | (wb & 0x7FFFFFFFu);
      if (key < best[9]) insert10(best, key);
    }

    // butterfly merge across the 16-lane group (exact: keys unique, order-free)
#pragma unroll
    for (int s = 1; s < 16; s <<= 1) {
      dens += __shfl_xor(dens, s, 16);
      u64 ok[10];
#pragma unroll
      for (int j = 0; j < 10; ++j) ok[j] = __shfl_xor(best[j], s, 16);
#pragma unroll
      for (int j = 0; j < 10; ++j) {
        if (ok[j] < best[9]) insert10(best, ok[j]); else break;
      }
    }

    if (active && sub == 0) {
      const float dist9 = __uint_as_float((unsigned)(best[9] >> 32));
      if (dist9 < 2.0f * HCELL * 0.999f) {
        flags[b * N_PTS + qidx] = 0;
        geom_epilogue(P, best, dens, px, py, pz, ctr, geom + ((size_t)b * N_PTS + qidx) * 6);
      } else {
        flags[b * N_PTS + qidx] = 1;
      }
    }
  }
}

// ---------------------------------------------------------------------------
// Fallback: exact R2 ring-scan, gated on flag (runs for ~0 queries normally)
__global__ __launch_bounds__(256) void k_fallback(const float* __restrict__ points,
                                                  const float4* __restrict__ sorted,
                                                  const int* __restrict__ start,
                                                  const float* __restrict__ center,
                                                  float* __restrict__ geom,
                                                  const int* __restrict__ flags) {
  const int b = blockIdx.y;
  const int qs = blockIdx.x * 256 + threadIdx.x;
  const float4 qp = sorted[(size_t)b * N_PTS + qs];
  const unsigned qw = __float_as_uint(qp.w);
  const int qidx = (int)(qw & 0x7FFFFFFFu);
  if (flags[b * N_PTS + qidx] == 0) return;

  const float px = qp.x, py = qp.y, pz = qp.z;
  const float sqq = sq3(px, py, pz);
  const int cx = cellOf(px), cy = cellOf(py), cz = cellOf(pz);

  const int* ST = start + b * (NCELL + 1);
  const float4* SP = sorted + (size_t)b * N_PTS;

  u64 best[10];
#pragma unroll
  for (int j = 0; j < 10; ++j) best[j] = ((u64)0x7F800000u << 32) | 0xFFFFFFFFu;
  float dens = 0.0f;

  for (int rho = 0; rho < GDIM; ++rho) {
    const int zlo = max(cz - rho, 0), zhi = min(cz + rho, GDIM - 1);
    const int ylo = max(cy - rho, 0), yhi = min(cy + rho, GDIM - 1);
    for (int z = zlo; z <= zhi; ++z) {
      const int adz = abs(z - cz);
      for (int y = ylo; y <= yhi; ++y) {
        const int ady = abs(y - cy);
        const int m2 = max(adz, ady);
        int ja, jb;
        int ja2 = 0, jb2 = 0;
        const int rowBase = (z * GDIM + y) * GDIM;
        if (m2 == rho) {
          const int xa = max(cx - rho, 0), xb = min(cx + rho, GDIM - 1);
          ja = ST[rowBase + xa]; jb = ST[rowBase + xb + 1];
        } else {
          ja = jb = 0;
          if (cx - rho >= 0)        { ja = ST[rowBase + cx - rho]; jb = ST[rowBase + cx - rho + 1]; }
          if (cx + rho <= GDIM - 1) { ja2 = ST[rowBase + cx + rho]; jb2 = ST[rowBase + cx + rho + 1]; }
        }
#pragma unroll 1
        for (int pass = 0; pass < 2; ++pass) {
          const int j0 = pass ? ja2 : ja;
          const int j1 = pass ? jb2 : jb;
          for (int j = j0; j < j1; ++j) {
            const float4 tp = SP[j];
            const unsigned wb = __float_as_uint(tp.w);
            const float sqc = sq3(tp.x, tp.y, tp.z);
            const float dot = __fmaf_rn(pz, tp.z, __fmaf_rn(py, tp.y, __fmul_rn(px, tp.x)));
            const float d2  = __fsub_rn(__fadd_rn(sqq, sqc), __fmul_rn(2.0f, dot));
            const float dist = sqrtf(fmaxf(d2, 0.0f));
            if ((dist < RADIUS_F) && (wb & 0x80000000u)) dens += 1.0f;
            const u64 key = ((u64)__float_as_uint(dist) << 32) | (wb & 0x7FFFFFFFu);
            if (key < best[9]) insert10(best, key);
          }
        }
      }
    }
    if (rho >= 1) {
      const float dist9 = __uint_as_float((unsigned)(best[9] >> 32));
      if (dist9 < (float)rho * HCELL * 0.999f) break;
    }
  }

  const float4 ctr = reinterpret_cast<const float4*>(center)[b];
  const float* P = points + (size_t)b * N_PTS * 3;
  geom_epilogue(P, best, dens, px, py, pz, ctr, geom + ((size_t)b * N_PTS + qidx) * 6);
}

// ---------------------------------------------------------------------------
// Kernel 3: fused 2-layer MLP (unchanged).
__global__ __launch_bounds__(256) void k_mlp(const float* __restrict__ features,
                                             const float* __restrict__ geom,
                                             const float* __restrict__ W1,
                                             const float* __restrict__ b1,
                                             const float* __restrict__ W2,
                                             const float* __restrict__ b2,
                                             float* __restrict__ out) {
  __shared__ float A[64][74];
  __shared__ float H[64][130];
  const int tid = threadIdx.x;
  const int row0 = blockIdx.x * 64;

  for (int i = tid; i < 64 * IN_DIM; i += 256) {
    int r = i >> 6, k = i & 63;
    A[r][k] = features[(size_t)(row0 + r) * IN_DIM + k];
  }
  for (int i = tid; i < 64 * 8; i += 256) {
    int r = i >> 3, k = i & 7;
    if (k < 6) A[r][IN_DIM + k] = geom[(size_t)(row0 + r) * 6 + k];
  }
  __syncthreads();

  const int ty = tid >> 4;
  const int tx = tid & 15;

  float acc[4][8];
#pragma unroll
  for (int i = 0; i < 4; ++i)
#pragma unroll
    for (int j = 0; j < 8; ++j) acc[i][j] = 0.0f;

#pragma unroll 2
  for (int k = 0; k < D_IN; ++k) {
    float a[4];
#pragma unroll
    for (int i = 0; i < 4; ++i) a[i] = A[ty * 4 + i][k];
    float4 w0 = *reinterpret_cast<const float4*>(&W1[(size_t)k * ODIM + tx * 8]);
    float4 w1 = *reinterpret_cast<const float4*>(&W1[(size_t)k * ODIM + tx * 8 + 4]);
    float w[8] = {w0.x, w0.y, w0.z, w0.w, w1.x, w1.y, w1.z, w1.w};
#pragma unroll
    for (int i = 0; i < 4; ++i)
#pragma unroll
      for (int j = 0; j < 8; ++j) acc[i][j] = fmaf(a[i], w[j], acc[i][j]);
  }

  {
    float4 bb0 = *reinterpret_cast<const float4*>(&b1[tx * 8]);
    float4 bb1 = *reinterpret_cast<const float4*>(&b1[tx * 8 + 4]);
    float bb[8] = {bb0.x, bb0.y, bb0.z, bb0.w, bb1.x, bb1.y, bb1.z, bb1.w};
#pragma unroll
    for (int i = 0; i < 4; ++i) {
      float4 h0 = make_float4(fmaxf(acc[i][0] + bb[0], 0.f), fmaxf(acc[i][1] + bb[1], 0.f),
                              fmaxf(acc[i][2] + bb[2], 0.f), fmaxf(acc[i][3] + bb[3], 0.f));
      float4 h1 = make_float4(fmaxf(acc[i][4] + bb[4], 0.f), fmaxf(acc[i][5] + bb[5], 0.f),
                              fmaxf(acc[i][6] + bb[6], 0.f), fmaxf(acc[i][7] + bb[7], 0.f));
      *reinterpret_cast<float4*>(&H[ty * 4 + i][tx * 8]) = h0;
      *reinterpret_cast<float4*>(&H[ty * 4 + i][tx * 8 + 4]) = h1;
    }
  }
  __syncthreads();

#pragma unroll
  for (int i = 0; i < 4; ++i)
#pragma unroll
    for (int j = 0; j < 8; ++j) acc[i][j] = 0.0f;

#pragma unroll 2
  for (int k = 0; k < ODIM; ++k) {
    float a[4];
#pragma unroll
    for (int i = 0; i < 4; ++i) a[i] = H[ty * 4 + i][k];
    float4 w0 = *reinterpret_cast<const float4*>(&W2[(size_t)k * ODIM + tx * 8]);
    float4 w1 = *reinterpret_cast<const float4*>(&W2[(size_t)k * ODIM + tx * 8 + 4]);
    float w[8] = {w0.x, w0.y, w0.z, w0.w, w1.x, w1.y, w1.z, w1.w};
#pragma unroll
    for (int i = 0; i < 4; ++i)
#pragma unroll
      for (int j = 0; j < 8; ++j) acc[i][j] = fmaf(a[i], w[j], acc[i][j]);
  }

  {
    float4 bb0 = *reinterpret_cast<const float4*>(&b2[tx * 8]);
    float4 bb1 = *reinterpret_cast<const float4*>(&b2[tx * 8 + 4]);
    float bb[8] = {bb0.x, bb0.y, bb0.z, bb0.w, bb1.x, bb1.y, bb1.z, bb1.w};
#pragma unroll
    for (int i = 0; i < 4; ++i) {
      size_t row = (size_t)(row0 + ty * 4 + i);
      float4 o0 = make_float4(fmaxf(acc[i][0] + bb[0], 0.f), fmaxf(acc[i][1] + bb[1], 0.f),
                              fmaxf(acc[i][2] + bb[2], 0.f), fmaxf(acc[i][3] + bb[3], 0.f));
      float4 o1 = make_float4(fmaxf(acc[i][4] + bb[4], 0.f), fmaxf(acc[i][5] + bb[5], 0.f),
                              fmaxf(acc[i][6] + bb[6], 0.f), fmaxf(acc[i][7] + bb[7], 0.f));
      *reinterpret_cast<float4*>(&out[row * ODIM + tx * 8]) = o0;
      *reinterpret_cast<float4*>(&out[row * ODIM + tx * 8 + 4]) = o1;
    }
  }
}

// ---------------------------------------------------------------------------
extern "C" void kernel_launch(void* const* d_in, const int* in_sizes, int n_in,
                              void* d_out, int out_size, void* d_ws, size_t ws_size,
                              hipStream_t stream) {
  const float* points   = (const float*)d_in[0];
  const float* features = (const float*)d_in[1];
  const int*   mask     = (const int*)d_in[2];
  const float* W1       = (const float*)d_in[3];
  const float* b1       = (const float*)d_in[4];
  const float* W2       = (const float*)d_in[5];
  const float* b2       = (const float*)d_in[6];
  float* out = (float*)d_out;

  // ws layout (all 256B aligned):
  char* w = (char*)d_ws;
  size_t off = 0;
  auto take = [&](size_t bytes) { char* p = w + off; off = (off + bytes + 255) & ~(size_t)255; return p; };
  float*  geomBuf   = (float*)take((size_t)NQ_ALL * 6 * 4);
  float*  centerBuf = (float*)take(2 * 16);
  int*    countBuf  = (int*)take((size_t)B_SZ * NCELL * 4);
  int*    startBuf  = (int*)take((size_t)B_SZ * (NCELL + 1) * 4);
  int*    curBuf    = (int*)take((size_t)B_SZ * NCELL * 4);
  float4* sortedBuf = (float4*)take((size_t)B_SZ * N_PTS * 16);
  int*    flagsBuf  = (int*)take((size_t)NQ_ALL * 4);
  (void)ws_size;

  hipMemsetAsync(countBuf, 0, (size_t)B_SZ * NCELL * 4, stream);
  k_center<<<B_SZ, 256, 0, stream>>>(points, mask, centerBuf);
  k_grid_count<<<NQ_ALL / 256, 256, 0, stream>>>(points, countBuf);
  k_scan<<<B_SZ, 1024, 0, stream>>>(countBuf, startBuf, curBuf);
  k_scatter<<<NQ_ALL / 256, 256, 0, stream>>>(points, mask, curBuf, sortedBuf);
  k_qsuper<<<dim3(NSUPER, B_SZ), 256, 0, stream>>>(points, sortedBuf, startBuf, centerBuf, geomBuf, flagsBuf);
  k_fallback<<<dim3(N_PTS / 256, B_SZ), 256, 0, stream>>>(points, sortedBuf, startBuf, centerBuf, geomBuf, flagsBuf);
  k_mlp<<<NQ_ALL / 64, 256, 0, stream>>>(features, geomBuf, W1, b1, W2, b2, out);
}